// Round 2
// baseline (151.922 us; speedup 1.0000x reference)
//
#include <hip/hip_runtime.h>
#include <stdint.h>

// Q2Linear int8 path, 2 dispatches — R13: R12 + B read direct from L2 (no LDS).
//   prep: blocks 0..1023    — per-row quantize x fp32 -> i8 (q = rowmax/127)
//         blocks 1024..5119 — pack w int32 {-2..1} -> i8 (exact, coalesced)
//   q8_gemm: i8 MFMA 32x32x32, tile 64m x 128n, BK=128, 512 blocks (2/CU).
//     A staged via global_load_lds(16B) into XOR-swizzled dbuf LDS (4x wave reuse).
//     B: each row consumed by exactly ONE lane -> zero intra-block reuse, and the
//     per-XCD B strip is 2MB = L2-resident (XCD pinning). So B skips LDS entirely:
//     per-lane contiguous row stream from global with 1-iteration register
//     prefetch (bvA/bvB named sets, static indexing). LDS traffic/block-it
//     72KB -> 40KB (-44%); DMA queue 6 -> 2 loads/lane; no B swizzle needed.
// Fragment maps (verified conventions): A/B row = lane&31, k-chunk = lane>>5;
// C/D col = lane&31, row = (reg&3) + 8*(reg>>2) + 4*(lane>>5).
// Ledger: R8 2-bit B -36%; R9 64x64/4-blk -2.7x; R10 direct-A no-prefetch -2x;
// R11=R7 143.0; R12 32x32 MFMA + setprio null (144.1) -> not MFMA-issue-bound.
// Timed region carries ~83us harness poison fills; kernels ~60us (prep ~16.5 at
// BW floor, gemm ~43 vs ~22us LDS-port floor -> this round attacks LDS traffic).

#define MM 1024
#define NN 4096
#define KK 4096
#define BK 128

typedef __attribute__((ext_vector_type(4))) int intx4;
typedef __attribute__((ext_vector_type(16))) int intx16;
typedef __attribute__((ext_vector_type(4))) float floatx4;
typedef __attribute__((ext_vector_type(16))) float floatx16;

typedef const __attribute__((address_space(1))) void global_cvoid;
typedef __attribute__((address_space(3))) void lds_void;

// ---- prep: quantize x (blocks < MM) OR pack w -> i8 --------------------------
__global__ __launch_bounds__(256) void prep(const float* __restrict__ x,
                                            const int* __restrict__ wq,
                                            char* __restrict__ xq,
                                            float* __restrict__ qrow,
                                            char* __restrict__ wb) {
    const int tid = threadIdx.x;
    if (blockIdx.x < MM) {
        const int m = blockIdx.x;
        const float* xr = x + (size_t)m * KK;
        floatx4 v[4];
        float amax = 0.f;
#pragma unroll
        for (int c = 0; c < 4; ++c) {
            v[c] = *(const floatx4*)(xr + (c * 256 + tid) * 4);
#pragma unroll
            for (int e = 0; e < 4; ++e) amax = fmaxf(amax, fabsf(v[c][e]));
        }
#pragma unroll
        for (int off = 32; off; off >>= 1) amax = fmaxf(amax, __shfl_down(amax, off));
        __shared__ float wmax[4];
        if ((tid & 63) == 0) wmax[tid >> 6] = amax;
        __syncthreads();
        amax = fmaxf(fmaxf(wmax[0], wmax[1]), fmaxf(wmax[2], wmax[3]));
        amax = fmaxf(amax, 1e-20f);
        const float qinv = 127.0f / amax;
        if (tid == 0) qrow[m] = amax / 127.0f;
#pragma unroll
        for (int c = 0; c < 4; ++c) {
            int p = 0;
#pragma unroll
            for (int e = 0; e < 4; ++e) {
                float r = rintf(v[c][e] * qinv);
                r = fminf(fmaxf(r, -127.f), 127.f);
                p |= ((int)r & 255) << (8 * e);
            }
            *(int*)(xq + (size_t)m * KK + (c * 256 + tid) * 4) = p;
        }
    } else {
        // pack w: fully coalesced (lane-consecutive 16B reads / 4B writes)
        const int blk = blockIdx.x - MM;
#pragma unroll
        for (int c = 0; c < 4; ++c) {
            size_t c4 = (size_t)blk * 1024 + c * 256 + tid;  // intx4-chunk id
            intx4 a = ((const intx4*)wq)[c4];
            ((int*)wb)[c4] = (a[0] & 255) | ((a[1] & 255) << 8) |
                             ((a[2] & 255) << 16) | (a[3] << 24);
        }
    }
}

// ---- GEMM: 64x128 tile, 4 waves (each 64m x 32n), A in dbuf LDS, B direct ----
__global__ __launch_bounds__(256, 2) void q8_gemm(const char* __restrict__ xq,
                                                  const char* __restrict__ wb,
                                                  const float* __restrict__ qrow,
                                                  const float* __restrict__ scales,
                                                  float* __restrict__ out) {
    __shared__ char As[2][64 * BK];    // 8 KB each
    __shared__ float Sl[128 * 33];     // scales [n_local][block], +1 pad (16.9 KB)
    // total 32.9 KB (B no longer staged)

    const int tid  = threadIdx.x;
    const int lane = tid & 63;
    const int wave = tid >> 6;
    const int l31  = lane & 31;        // A/B fragment row, C/D col (n)
    const int hi   = lane >> 5;        // k-chunk half selector
    const int sw   = lane & 7;         // swizzle key == row&7 (A LDS reads only)
    const int wn   = wave * 32;        // wave's n offset within tile

    // XCD pinning: bid&7 -> XCD; each XCD owns 4 n-tiles (512 cols, 2MB i8 B-strip)
    const int bid = blockIdx.x;
    const int xcd = bid & 7, loc = bid >> 3;   // loc 0..63
    const int nT = xcd * 4 + (loc & 3);        // 0..31
    const int mT = loc >> 2;                   // 0..15
    const int mBase = mT * 64, nBase = nT * 128;

    // A staging address permute -> XOR-swizzled LDS tile (verified, 0 conflicts)
    const int rg = lane >> 3;
    const int cs = (lane & 7) ^ rg;
    const char* gA = xq + (size_t)(mBase + wave * 16 + rg) * KK + cs * 16;
    const int ldsRowA = wave * 16;

    // B: this lane's private row stream (no swizzle — straight from global/L2)
    const char* gBrow = wb + (size_t)(nBase + wn + l31) * KK + hi * 16;

    floatx16 fac0, fac1;
#pragma unroll
    for (int r = 0; r < 16; ++r) { fac0[r] = 0.f; fac1[r] = 0.f; }

#define STAGE_A(BUF, SLAB)                                                      \
    {                                                                           \
        _Pragma("unroll")                                                       \
        for (int t = 0; t < 2; ++t)                                             \
            __builtin_amdgcn_global_load_lds(                                   \
                (global_cvoid*)(gA + (size_t)(t * 8) * KK + (SLAB) * BK),       \
                (lds_void*)&As[BUF][(ldsRowA + t * 8) * BK], 16, 0, 0);         \
    }

#define LOAD_B(BV, SLAB)                                                        \
    {                                                                           \
        _Pragma("unroll")                                                       \
        for (int kp = 0; kp < 4; ++kp)                                          \
            BV[kp] = *(const intx4*)(gBrow + (size_t)(SLAB) * BK + kp * 32);    \
    }

    // per kp: av rows l31 / 32+l31 from swizzled LDS, bv from registers.
    // 8 ds_read_b128 + 8 MFMA per it (was 12 + 8 with B staged).
#define COMPUTE(BUF, SLAB, BV)                                                  \
    {                                                                           \
        const float sf = Sl[(wn + l31) * 33 + (SLAB)];                          \
        intx16 iacc0, iacc1;                                                    \
        __builtin_amdgcn_s_setprio(1);                                          \
        _Pragma("unroll")                                                       \
        for (int kp = 0; kp < 4; ++kp) {                                        \
            const int kc = (((kp * 2) + hi) ^ sw) << 4;                         \
            intx4 av0 = *(const intx4*)&As[BUF][l31 * BK + kc];                 \
            intx4 av1 = *(const intx4*)&As[BUF][(32 + l31) * BK + kc];          \
            const int kq = ((kp * 2) + hi) >> 1;  /* register bv index = kp */  \
            (void)kq;                                                           \
            if (kp == 0) {                                                      \
                intx16 z = {0, 0, 0, 0, 0, 0, 0, 0, 0, 0, 0, 0, 0, 0, 0, 0};    \
                iacc0 = __builtin_amdgcn_mfma_i32_32x32x32_i8(av0, BV[kp], z, 0, 0, 0); \
                iacc1 = __builtin_amdgcn_mfma_i32_32x32x32_i8(av1, BV[kp], z, 0, 0, 0); \
            } else {                                                            \
                iacc0 = __builtin_amdgcn_mfma_i32_32x32x32_i8(av0, BV[kp], iacc0, 0, 0, 0); \
                iacc1 = __builtin_amdgcn_mfma_i32_32x32x32_i8(av1, BV[kp], iacc1, 0, 0, 0); \
            }                                                                   \
        }                                                                       \
        __builtin_amdgcn_s_setprio(0);                                          \
        _Pragma("unroll")                                                       \
        for (int r = 0; r < 16; ++r) {                                          \
            fac0[r] += (float)iacc0[r] * sf;                                    \
            fac1[r] += (float)iacc1[r] * sf;                                    \
        }                                                                       \
    }

    // IMPORTANT on A LDS av reads vs B register chunks:
    //   av at swizzled chunk ((kp*2+hi)^sw) holds A k-bytes (kp*2+hi)*16..+15,
    //   i.e. k = kp*32 + hi*16 within the slab — exactly the bytes LOAD_B fetched
    //   for BV[kp] (gBrow already folds hi*16). Same pairing as the staged path.

    intx4 bvA[4], bvB[4];
    STAGE_A(0, 0)
    LOAD_B(bvA, 0)
    // stage scales once: coalesced global read; LDS banks (nl+b)%32 -> 2-way = free
    for (int t = tid; t < 4096; t += 256) {
        int nl = t >> 5, b = t & 31;
        Sl[nl * 33 + b] = scales[(size_t)(nBase + nl) * 32 + b];
    }
    __syncthreads();

    const int NIT = KK / BK;  // 32
    for (int it = 0; it < NIT; it += 2) {
        if (it + 1 < NIT) { STAGE_A(1, it + 1) LOAD_B(bvB, it + 1) }
        COMPUTE(0, it, bvA)
        __syncthreads();
        if (it + 2 < NIT) { STAGE_A(0, it + 2) LOAD_B(bvA, it + 2) }
        COMPUTE(1, it + 1, bvB)
        __syncthreads();
    }

    // epilogue: C/D col = lane&31 (n), row = (reg&3)+8*(reg>>2)+4*hi (m); fold q[m]
#pragma unroll
    for (int g = 0; g < 4; ++g) {
        floatx4 qv0 = *(const floatx4*)(qrow + mBase + g * 8 + hi * 4);
        floatx4 qv1 = *(const floatx4*)(qrow + mBase + 32 + g * 8 + hi * 4);
#pragma unroll
        for (int r = 0; r < 4; ++r) {
            const int m0 = mBase + g * 8 + hi * 4 + r;
            out[(size_t)m0 * NN + nBase + wn + l31]        = fac0[g * 4 + r] * qv0[r];
            out[(size_t)(m0 + 32) * NN + nBase + wn + l31] = fac1[g * 4 + r] * qv1[r];
        }
    }
#undef STAGE_A
#undef LOAD_B
#undef COMPUTE
}

extern "C" void kernel_launch(void* const* d_in, const int* in_sizes, int n_in,
                              void* d_out, int out_size, void* d_ws, size_t ws_size,
                              hipStream_t stream) {
    const float* x      = (const float*)d_in[0];
    const int*   wq     = (const int*)d_in[1];
    const float* scales = (const float*)d_in[2];
    float*       out    = (float*)d_out;

    char*  xq   = (char*)d_ws;                                   // 4 MB
    float* qrow = (float*)((char*)d_ws + (size_t)MM * KK);       // 4 KB
    char*  wb   = (char*)d_ws + (size_t)MM * KK + 4096;          // 16.8 MB

    prep<<<MM + (size_t)NN * KK / 16 / 256, 256, 0, stream>>>(x, wq, xq, qrow, wb);
    q8_gemm<<<(MM / 64) * (NN / 128), 256, 0, stream>>>(xq, wb, qrow, scales, out);
}

// Round 3
// 146.235 us; speedup vs baseline: 1.0389x; 1.0389x over previous
//
#include <hip/hip_runtime.h>
#include <stdint.h>

// Q2Linear int8 path, 2 dispatches — R14: counted-vmcnt triple-buffer pipeline (T3+T4).
//   prep: unchanged (quantize x -> i8; pack w int32 -> i8). ~17us, at BW floor.
//   q8_gemm: i8 MFMA 32x32x32, tile 64m x 128n, BK=128, 512 blocks (2/CU).
//     B restored to LDS (R13 direct-B regressed: scattered row streams + vmcnt(0)
//     drain exposed L2 latency; MfmaUtil 14 / VALU 16 / HBM 11% = latency-bound).
//     NEW: 3-deep LDS buffers (72KB, 2 blk/CU), 2 slabs prefetched ahead, raw
//     s_barrier + counted `s_waitcnt vmcnt(14)` — loads NEVER drained to 0 in the
//     main loop (T4). Per slab/wave: 7 vm-ops in fixed order (6 global_load_lds +
//     1 scale dword from L2; Sl LDS staging dropped to fit 3 bufs), so outstanding
//     is 21 steady-state and vmcnt(14) retires exactly the current slab.
//     Slab phase: vmcnt(14); barrier; 12x ds_read_b128 burst; lgkmcnt(0)+SGB;
//     barrier; STAGE(slab+3) into cur buf (race-free: all reads done); setprio(1)
//     8x MFMA setprio(0); VALU fold. 2 barriers/slab, no full drains.
// Fragment maps: A/B row = lane&31, k-chunk = lane>>5; C/D col = lane&31,
// row = (reg&3) + 8*(reg>>2) + 4*(lane>>5).
// Ledger: R8 -36%; R9 64x64 -2.7x; R10 direct-A -2x; R11=R7 143.0;
// R12 32x32+setprio null (144.1, not MFMA-issue-bound); R13 direct-B 151.9
// (latency-bound diagnosis: all pipes <20%). Timed region: ~83us harness fills
// + prep ~17 + gemm ~41 (this round's target: gemm -> ~30 via T3/T4).

#define MM 1024
#define NN 4096
#define KK 4096
#define BK 128

typedef __attribute__((ext_vector_type(4))) int intx4;
typedef __attribute__((ext_vector_type(16))) int intx16;
typedef __attribute__((ext_vector_type(4))) float floatx4;
typedef __attribute__((ext_vector_type(16))) float floatx16;

typedef const __attribute__((address_space(1))) void global_cvoid;
typedef __attribute__((address_space(3))) void lds_void;

// ---- prep: quantize x (blocks < MM) OR pack w -> i8 --------------------------
__global__ __launch_bounds__(256) void prep(const float* __restrict__ x,
                                            const int* __restrict__ wq,
                                            char* __restrict__ xq,
                                            float* __restrict__ qrow,
                                            char* __restrict__ wb) {
    const int tid = threadIdx.x;
    if (blockIdx.x < MM) {
        const int m = blockIdx.x;
        const float* xr = x + (size_t)m * KK;
        floatx4 v[4];
        float amax = 0.f;
#pragma unroll
        for (int c = 0; c < 4; ++c) {
            v[c] = *(const floatx4*)(xr + (c * 256 + tid) * 4);
#pragma unroll
            for (int e = 0; e < 4; ++e) amax = fmaxf(amax, fabsf(v[c][e]));
        }
#pragma unroll
        for (int off = 32; off; off >>= 1) amax = fmaxf(amax, __shfl_down(amax, off));
        __shared__ float wmax[4];
        if ((tid & 63) == 0) wmax[tid >> 6] = amax;
        __syncthreads();
        amax = fmaxf(fmaxf(wmax[0], wmax[1]), fmaxf(wmax[2], wmax[3]));
        amax = fmaxf(amax, 1e-20f);
        const float qinv = 127.0f / amax;
        if (tid == 0) qrow[m] = amax / 127.0f;
#pragma unroll
        for (int c = 0; c < 4; ++c) {
            int p = 0;
#pragma unroll
            for (int e = 0; e < 4; ++e) {
                float r = rintf(v[c][e] * qinv);
                r = fminf(fmaxf(r, -127.f), 127.f);
                p |= ((int)r & 255) << (8 * e);
            }
            *(int*)(xq + (size_t)m * KK + (c * 256 + tid) * 4) = p;
        }
    } else {
        // pack w: fully coalesced (lane-consecutive 16B reads / 4B writes)
        const int blk = blockIdx.x - MM;
#pragma unroll
        for (int c = 0; c < 4; ++c) {
            size_t c4 = (size_t)blk * 1024 + c * 256 + tid;  // intx4-chunk id
            intx4 a = ((const intx4*)wq)[c4];
            ((int*)wb)[c4] = (a[0] & 255) | ((a[1] & 255) << 8) |
                             ((a[2] & 255) << 16) | (a[3] << 24);
        }
    }
}

// ---- GEMM: 64x128 tile, 4 waves, 3-deep LDS pipeline, counted vmcnt ----------
__global__ __launch_bounds__(256, 2) void q8_gemm(const char* __restrict__ xq,
                                                  const char* __restrict__ wb,
                                                  const float* __restrict__ qrow,
                                                  const float* __restrict__ scales,
                                                  float* __restrict__ out) {
    __shared__ char As[3][64 * BK];    // 8 KB each  -> 24 KB
    __shared__ char Bs[3][128 * BK];   // 16 KB each -> 48 KB
    // total 72 KB -> 2 blocks/CU (scales read direct from L2, no Sl)

    const int tid  = threadIdx.x;
    const int lane = tid & 63;
    const int wave = tid >> 6;
    const int l31  = lane & 31;        // A/B fragment row, C/D col (n)
    const int hi   = lane >> 5;        // k-chunk half selector
    const int sw   = lane & 7;         // XOR-swizzle key (== row&7 for all reads)
    const int wn   = wave * 32;        // wave's n offset within tile

    // XCD pinning: bid&7 -> XCD; each XCD owns 4 n-tiles (512 cols, 2MB i8 B-strip)
    const int bid = blockIdx.x;
    const int xcd = bid & 7, loc = bid >> 3;   // loc 0..63
    const int nT = xcd * 4 + (loc & 3);        // 0..31
    const int mT = loc >> 2;                   // 0..15
    const int mBase = mT * 64, nBase = nT * 128;

    // staging address permute -> XOR-swizzled LDS tile
    const int rg = lane >> 3;
    const int cs = (lane & 7) ^ rg;
    const char* gA = xq + (size_t)(mBase + wave * 16 + rg) * KK + cs * 16;
    const char* gB = wb + (size_t)(nBase + wave * 32 + rg) * KK + cs * 16;
    const int ldsRowA = wave * 16;
    const int ldsRowB = wave * 32;

    const float* scrow = scales + (size_t)(nBase + wn + l31) * 32;

    floatx16 fac0, fac1;
#pragma unroll
    for (int r = 0; r < 16; ++r) { fac0[r] = 0.f; fac1[r] = 0.f; }

#define STAGE_DMA(BUF, SLAB)                                                    \
    {                                                                           \
        _Pragma("unroll")                                                       \
        for (int t = 0; t < 2; ++t)                                             \
            __builtin_amdgcn_global_load_lds(                                   \
                (global_cvoid*)(gA + (size_t)(t * 8) * KK + (size_t)(SLAB) * BK),\
                (lds_void*)&As[BUF][(ldsRowA + t * 8) * BK], 16, 0, 0);         \
        _Pragma("unroll")                                                       \
        for (int t = 0; t < 4; ++t)                                             \
            __builtin_amdgcn_global_load_lds(                                   \
                (global_cvoid*)(gB + (size_t)(t * 8) * KK + (size_t)(SLAB) * BK),\
                (lds_void*)&Bs[BUF][(ldsRowB + t * 8) * BK], 16, 0, 0);         \
    }

    // One pipeline step: compute slab in BUF; optionally stage slab JNXT into the
    // SAME buf (safe: issued after all waves' lgkm-complete reads + barrier).
    // WAITN literal: outstanding vm-ops to leave in flight (7 per staged slab).
#define STEP(BUF, WAITN, DO_STAGE, JNXT, SC)                                    \
    {                                                                           \
        asm volatile("s_waitcnt vmcnt(" #WAITN ")" ::: "memory");               \
        __builtin_amdgcn_s_barrier();                                           \
        intx4 av0[4], av1[4], bv[4];                                            \
        _Pragma("unroll")                                                       \
        for (int kp = 0; kp < 4; ++kp) {                                        \
            const int kc = (((kp * 2) + hi) ^ sw) << 4;                         \
            av0[kp] = *(const intx4*)&As[BUF][l31 * BK + kc];                   \
            av1[kp] = *(const intx4*)&As[BUF][(32 + l31) * BK + kc];            \
            bv[kp]  = *(const intx4*)&Bs[BUF][(wn + l31) * BK + kc];            \
        }                                                                       \
        asm volatile("s_waitcnt lgkmcnt(0)" ::: "memory");                      \
        __builtin_amdgcn_sched_barrier(0);                                      \
        __builtin_amdgcn_s_barrier();                                           \
        if (DO_STAGE) { STAGE_DMA(BUF, JNXT) }                                  \
        asm volatile("" ::: "memory");                                          \
        intx16 iacc0, iacc1;                                                    \
        __builtin_amdgcn_s_setprio(1);                                          \
        _Pragma("unroll")                                                       \
        for (int kp = 0; kp < 4; ++kp) {                                        \
            if (kp == 0) {                                                      \
                intx16 z = {0, 0, 0, 0, 0, 0, 0, 0, 0, 0, 0, 0, 0, 0, 0, 0};    \
                iacc0 = __builtin_amdgcn_mfma_i32_32x32x32_i8(av0[0], bv[0], z, 0, 0, 0); \
                iacc1 = __builtin_amdgcn_mfma_i32_32x32x32_i8(av1[0], bv[0], z, 0, 0, 0); \
            } else {                                                            \
                iacc0 = __builtin_amdgcn_mfma_i32_32x32x32_i8(av0[kp], bv[kp], iacc0, 0, 0, 0); \
                iacc1 = __builtin_amdgcn_mfma_i32_32x32x32_i8(av1[kp], bv[kp], iacc1, 0, 0, 0); \
            }                                                                   \
        }                                                                       \
        __builtin_amdgcn_s_setprio(0);                                          \
        _Pragma("unroll")                                                       \
        for (int r = 0; r < 16; ++r) {                                          \
            fac0[r] += (float)iacc0[r] * (SC);                                  \
            fac1[r] += (float)iacc1[r] * (SC);                                  \
        }                                                                       \
        if (DO_STAGE) { SC = scrow[(JNXT)]; }                                   \
        asm volatile("" ::: "memory");                                          \
    }

    // prologue: stage slabs 0..2 (7 vm-ops each, fixed order D6+S1 per slab)
    float sc0, sc1, sc2;
    STAGE_DMA(0, 0) sc0 = scrow[0];
    asm volatile("" ::: "memory");
    STAGE_DMA(1, 1) sc1 = scrow[1];
    asm volatile("" ::: "memory");
    STAGE_DMA(2, 2) sc2 = scrow[2];
    asm volatile("" ::: "memory");

    // main: slabs 0..26 (9 x 3), staging 3..29; 2 slabs always in flight
    for (int base = 0; base < 27; base += 3) {
        STEP(0, 14, 1, base + 3, sc0)
        STEP(1, 14, 1, base + 4, sc1)
        STEP(2, 14, 1, base + 5, sc2)
    }
    // tail: slabs 27..31 (stage 30,31 then drain)
    STEP(0, 14, 1, 30, sc0)
    STEP(1, 14, 1, 31, sc1)
    STEP(2, 14, 0, 0, sc2)
    STEP(0, 7, 0, 0, sc0)
    STEP(1, 0, 0, 0, sc1)

    // epilogue: C/D col = lane&31 (n), row = (reg&3)+8*(reg>>2)+4*hi (m); fold q[m]
#pragma unroll
    for (int g = 0; g < 4; ++g) {
        floatx4 qv0 = *(const floatx4*)(qrow + mBase + g * 8 + hi * 4);
        floatx4 qv1 = *(const floatx4*)(qrow + mBase + 32 + g * 8 + hi * 4);
#pragma unroll
        for (int r = 0; r < 4; ++r) {
            const int m0 = mBase + g * 8 + hi * 4 + r;
            out[(size_t)m0 * NN + nBase + wn + l31]        = fac0[g * 4 + r] * qv0[r];
            out[(size_t)(m0 + 32) * NN + nBase + wn + l31] = fac1[g * 4 + r] * qv1[r];
        }
    }
#undef STAGE_DMA
#undef STEP
}

extern "C" void kernel_launch(void* const* d_in, const int* in_sizes, int n_in,
                              void* d_out, int out_size, void* d_ws, size_t ws_size,
                              hipStream_t stream) {
    const float* x      = (const float*)d_in[0];
    const int*   wq     = (const int*)d_in[1];
    const float* scales = (const float*)d_in[2];
    float*       out    = (float*)d_out;

    char*  xq   = (char*)d_ws;                                   // 4 MB
    float* qrow = (float*)((char*)d_ws + (size_t)MM * KK);       // 4 KB
    char*  wb   = (char*)d_ws + (size_t)MM * KK + 4096;          // 16.8 MB

    prep<<<MM + (size_t)NN * KK / 16 / 256, 256, 0, stream>>>(x, wq, xq, qrow, wb);
    q8_gemm<<<(MM / 64) * (NN / 128), 256, 0, stream>>>(xq, wb, qrow, scales, out);
}